// Round 4
// baseline (4460.011 us; speedup 1.0000x reference)
//
#include <hip/hip_runtime.h>
#include <hip/hip_fp16.h>

typedef _Float16 half8 __attribute__((ext_vector_type(8)));
typedef _Float16 half4v __attribute__((ext_vector_type(4)));
typedef float floatx4 __attribute__((ext_vector_type(4)));

#define T_    128
#define B_    64
#define HCH   128        // hidden channels
#define NQ    4608       // 128 ch * 36 (gate-interleaved cols: n = ch*36 + g*9 + p)
#define KH    1152       // HCH*9
#define NROWS 8192       // B_*T_

__device__ __forceinline__ float sigm(float x){ return 1.0f/(1.0f + __expf(-x)); }

__device__ __forceinline__ void gll16(const _Float16* g, const _Float16* l){
  __builtin_amdgcn_global_load_lds(
      (const __attribute__((address_space(1))) unsigned int*)g,
      (__attribute__((address_space(3))) unsigned int*)l, 16, 0, 0);
}

// ---------- pack: fp32 -> fp16 cast (vectorized x4) ----------
__global__ void k_cast_f16(const float* __restrict__ src, _Float16* __restrict__ dst, int n4){
  int i = blockIdx.x*blockDim.x + threadIdx.x;
  if (i >= n4) return;
  float4 v = ((const float4*)src)[i];
  half4v h;
  h[0] = (_Float16)v.x; h[1] = (_Float16)v.y; h[2] = (_Float16)v.z; h[3] = (_Float16)v.w;
  ((half4v*)dst)[i] = h;
}

// ---------- pack conv weights -> dense W2^T [N][K], gate-interleaved N ----------
// w: [4H][Cx+128][3][3].  Wx: [4608][Cx*9] (x-part, ci in [0,Cx)).
// Wh: [4620][1152] (h-part, ci_src = Cx+ci), rows 4608..4619 zero pad.
__global__ void k_pack_w2(const float* __restrict__ w, _Float16* __restrict__ Wx,
                          _Float16* __restrict__ Wh, int Cx, int total){
  int idx = blockIdx.x*256 + threadIdx.x;
  if (idx >= total) return;
  int Kx = Cx*9;
  int nWx = NQ*Kx;
  int n, kk, ci;
  _Float16* dst;
  bool pad = false;
  if (idx < nWx) { n = idx / Kx; kk = idx % Kx; ci = kk/9; dst = Wx + idx; }
  else {
    int e = idx - nWx;
    n = e / KH; kk = e % KH; ci = Cx + kk/9; dst = Wh + e;
    pad = (n >= NQ);
  }
  float val = 0.0f;
  if (!pad) {
    int ch = n/36, g = (n%36)/9, p = n%9, q = kk%9;
    int kr = q/3 - p/3 + 1, kc = q%3 - p%3 + 1;
    if (kr>=0 && kr<3 && kc>=0 && kc<3)
      val = w[(((g*HCH+ch)*(Cx+HCH) + ci)*3 + kr)*3 + kc];
  }
  *dst = (_Float16)val;
}

// ---------- pack biases into gate-interleaved order: [4][4608] ----------
__global__ void k_pack_bias(const float* __restrict__ b0f, const float* __restrict__ b0b,
                            const float* __restrict__ b1f, const float* __restrict__ b1b,
                            float* __restrict__ outb){
  int idx = blockIdx.x*256 + threadIdx.x;
  if (idx >= 4*NQ) return;
  int li = idx / NQ, n = idx % NQ;
  const float* src = (li==0)?b0f : (li==1)?b0b : (li==2)?b1f : b1b;
  int ch = n/36, g = (n%36)/9;
  outb[idx] = src[g*HCH + ch];
}

// ---------- x-part GEMM: Zx[dir][M][N] (fp16, bias folded) = A[M][K] * Bt[dir][N][K]^T ----------
// 128x128 tile, BK=32, 4 waves (2x2 of 64x64), mfma 16x16x32 f16, global_load_lds staging,
// XOR chunk swizzle (source-side + read-side, LDS linear) for bank spread.
__global__ __launch_bounds__(256) void k_gemm(
    const _Float16* __restrict__ A, const _Float16* __restrict__ Bt,
    _Float16* __restrict__ Co, const float* __restrict__ biasArr, int K)
{
  __shared__ _Float16 As[128*32];
  __shared__ _Float16 Bs[128*32];
  int flat = blockIdx.x;
  int cpx  = gridDim.x >> 3;                 // grid is 4608 (mult of 8): bijective XCD swizzle
  int swz  = (flat & 7)*cpx + (flat >> 3);
  int dir  = swz / (64*36);
  int rem  = swz % (64*36);
  size_t m0 = (size_t)(rem / 36) * 128;
  size_t n0 = (size_t)(rem % 36) * 128;
  const _Float16* Bd = Bt + (size_t)dir*NQ*K;
  _Float16*       Cd = Co + (size_t)dir*NROWS*NQ;
  const float* bias  = biasArr + dir*NQ;

  int tid = threadIdx.x;
  int w = tid >> 6, l = tid & 63;
  int wm = w >> 1, wn = w & 1;
  int lr = l & 15, lk = l >> 4;
  int sr = tid >> 2, sc = tid & 3;

  floatx4 acc[4][4] = {};
  for (int kt = 0; kt < K; kt += 32) {
    __syncthreads();
    {
      int r = sr;       int cg = sc ^ ((r>>1)&3);
      gll16(A  + (m0 + r)*K + kt + cg*8, As + r*32 + sc*8);
      r = sr + 64;      cg = sc ^ ((r>>1)&3);
      gll16(A  + (m0 + r)*K + kt + cg*8, As + r*32 + sc*8);
      r = sr;           cg = sc ^ ((r>>1)&3);
      gll16(Bd + (n0 + r)*K + kt + cg*8, Bs + r*32 + sc*8);
      r = sr + 64;      cg = sc ^ ((r>>1)&3);
      gll16(Bd + (n0 + r)*K + kt + cg*8, Bs + r*32 + sc*8);
    }
    __syncthreads();   // drains vmcnt(0) before barrier -> LDS data ready
    half8 a[4], b[4];
    #pragma unroll
    for (int mi=0; mi<4; ++mi){
      int row = wm*64 + mi*16 + lr;
      int sl  = lk ^ ((row>>1)&3);
      a[mi] = *(const half8*)(As + row*32 + sl*8);
    }
    #pragma unroll
    for (int ni=0; ni<4; ++ni){
      int row = wn*64 + ni*16 + lr;
      int sl  = lk ^ ((row>>1)&3);
      b[ni] = *(const half8*)(Bs + row*32 + sl*8);
    }
    #pragma unroll
    for (int mi=0; mi<4; ++mi)
      #pragma unroll
      for (int ni=0; ni<4; ++ni)
        acc[mi][ni] = __builtin_amdgcn_mfma_f32_16x16x32_f16(a[mi], b[ni], acc[mi][ni], 0,0,0);
  }
  #pragma unroll
  for (int mi=0; mi<4; ++mi)
    #pragma unroll
    for (int ni=0; ni<4; ++ni)
      #pragma unroll
      for (int j=0; j<4; ++j) {
        size_t m = m0 + wm*64 + mi*16 + lk*4 + j;   // D: col=lane&15, row=(lane>>4)*4+j
        size_t n = n0 + wn*64 + ni*16 + lr;
        Cd[m*NQ + n] = (_Float16)(acc[mi][ni][j] + bias[n]);
      }
}

// ---------- recurrent step: z = Hin*Wh + Zx ; gates ; update C, Hout, HS ----------
// 256 blocks = 2 dirs x 128 channels. Waves split K (288 each), operands direct from L2,
// cross-wave reduce + gate epilogue via LDS.
__global__ __launch_bounds__(256) void k_step(
    const _Float16* __restrict__ Wh,   // [2][4620][1152]
    const _Float16* __restrict__ Zx,   // [2][8192][4608] fp16, bias included
    const _Float16* __restrict__ Hin,  // [2][64][1152]
    _Float16* __restrict__ Hout,       // [2][64][1152]
    float* __restrict__ Cst,           // [2][64][1152]
    _Float16* __restrict__ HS,         // [2][128][64][1152]
    int s)
{
  __shared__ float red[4][64][52];     // pad 48->52
  int bid = blockIdx.x;
  int d = bid >> 7, ch = bid & 127;
  int t = d ? (T_-1-s) : s;
  int tid = threadIdx.x, w = tid >> 6, l = tid & 63;
  int lr = l & 15, lk = l >> 4;
  const _Float16* hb = Hin + (size_t)d*B_*KH;
  const _Float16* wb = Wh  + (size_t)d*4620*KH + (size_t)(ch*36)*KH;

  floatx4 acc[4][3] = {};
  #pragma unroll
  for (int ki = 0; ki < 9; ++ki) {
    int k = w*288 + ki*32 + lk*8;
    half8 a[4], b[3];
    #pragma unroll
    for (int mi=0; mi<4; ++mi) a[mi] = *(const half8*)(hb + (size_t)(mi*16+lr)*KH + k);
    #pragma unroll
    for (int ni=0; ni<3; ++ni) b[ni] = *(const half8*)(wb + (size_t)(ni*16+lr)*KH + k);
    #pragma unroll
    for (int mi=0; mi<4; ++mi)
      #pragma unroll
      for (int ni=0; ni<3; ++ni)
        acc[mi][ni] = __builtin_amdgcn_mfma_f32_16x16x32_f16(a[mi], b[ni], acc[mi][ni], 0,0,0);
  }
  #pragma unroll
  for (int mi=0; mi<4; ++mi)
    #pragma unroll
    for (int ni=0; ni<3; ++ni)
      #pragma unroll
      for (int j=0; j<4; ++j)
        red[w][mi*16 + lk*4 + j][ni*16 + lr] = acc[mi][ni][j];
  __syncthreads();

  for (int pi = tid; pi < 576; pi += 256) {
    int row = pi/9, p = pi%9;
    const _Float16* zr = Zx + (size_t)d*NROWS*NQ + (size_t)(row*T_ + t)*NQ + ch*36;
    float zv[4];
    #pragma unroll
    for (int g=0; g<4; ++g) {
      int c0 = g*9+p;
      zv[g] = red[0][row][c0]+red[1][row][c0]+red[2][row][c0]+red[3][row][c0] + (float)zr[c0];
    }
    size_t ii = (size_t)d*B_*KH + (size_t)row*KH + ch*9 + p;
    float co = Cst[ii];
    float cn = sigm(zv[1])*co + sigm(zv[0])*tanhf(zv[3]);
    float h  = sigm(zv[2])*tanhf(cn);
    Cst[ii]  = cn;
    Hout[ii] = (_Float16)h;
    HS[(size_t)((d*T_ + t)*B_ + row)*KH + ch*9 + p] = (_Float16)h;
  }
}

// ---------- layer-1 input: A1[(b*T+t)][k] = hs_f + hs_b (fp16) ----------
__global__ void k_pack_A1(const _Float16* __restrict__ hs, _Float16* __restrict__ A1, int nchunks){
  int i = blockIdx.x*256 + threadIdx.x;
  if (i >= nchunks) return;                 // chunks of 8 halves
  int r  = i / (KH/8);
  int kc = i % (KH/8);
  int b = r / T_, t = r % T_;
  half8 xv = ((const half8*)(hs + (size_t)(t*B_ + b)*KH))[kc];
  half8 yv = ((const half8*)(hs + (size_t)((T_ + t)*B_ + b)*KH))[kc];
  half8 o;
  #pragma unroll
  for (int e=0; e<8; ++e) o[e] = (_Float16)((float)xv[e] + (float)yv[e]);
  ((half8*)A1)[i] = o;
}

// ---------- final FC: out[b,t,nc] = (hs_f + hs_b) . fc_w[nc] + fc_b ----------
__global__ __launch_bounds__(64) void k_fc(const _Float16* __restrict__ hs,
                                           const float* __restrict__ fw,
                                           const float* __restrict__ fb,
                                           float* __restrict__ out){
  int r = blockIdx.x;            // b*T + t
  int b = r / T_, t = r % T_;
  int l = threadIdx.x;
  const _Float16* ha = hs + (size_t)(t*B_ + b)*KH;
  const _Float16* hc = hs + (size_t)((T_ + t)*B_ + b)*KH;
  float accv[7] = {0,0,0,0,0,0,0};
  for (int k=l; k<KH; k+=64){
    float h = (float)ha[k] + (float)hc[k];
    #pragma unroll
    for (int nc=0; nc<7; ++nc) accv[nc] += h * fw[nc*KH + k];
  }
  #pragma unroll
  for (int nc=0; nc<7; ++nc){
    float v = accv[nc];
    for (int off=32; off; off>>=1) v += __shfl_down(v, off, 64);
    if (l==0) out[(size_t)r*7 + nc] = v + fb[nc];
  }
}

extern "C" void kernel_launch(void* const* d_in, const int* in_sizes, int n_in,
                              void* d_out, int out_size, void* d_ws, size_t ws_size,
                              hipStream_t stream)
{
  const float* x    = (const float*)d_in[0];
  const float* w_f0 = (const float*)d_in[1];
  const float* b_f0 = (const float*)d_in[2];
  const float* w_b0 = (const float*)d_in[3];
  const float* b_b0 = (const float*)d_in[4];
  const float* w_f1 = (const float*)d_in[5];
  const float* b_f1 = (const float*)d_in[6];
  const float* w_b1 = (const float*)d_in[7];
  const float* b_b1 = (const float*)d_in[8];
  const float* fc_w = (const float*)d_in[9];
  const float* fc_b = (const float*)d_in[10];
  float* out = (float*)d_out;

  // ---- workspace arena with live-range aliasing (total 256,112,640 B = 244.25 MiB) ----
  // R_A (40,108,032): A0 [cast -> L0 gemm] ; then A1 (+0) & WxT1 (+18,874,368) [-> L1 gemm]
  // R1  (42,467,328): WxT0 [-> L0 gemm] ; then hs0 [L0 steps -> pack_A1] ; then hs1 [L1 steps -> FC]
  // R2 (150,994,944): Zx (both layers)
  // R3  (21,288,960): WhT0 [-> L0 steps] ; then WhT1 [packed after L0 steps -> L1 steps]
  char* base = (char*)d_ws;
  const size_t TOTAL = 256112640;
  if (ws_size < TOTAL) {                    // loud failure: absmax ~3.4e38 signals ws too small
    (void)hipMemsetAsync(d_out, 0x7F, (size_t)out_size*4, stream);
    return;
  }
  _Float16* A0   = (_Float16*)(base);                     // 37,748,736 used of R_A
  _Float16* A1   = (_Float16*)(base);                     // alias (after A0 dead)
  _Float16* WxT1 = (_Float16*)(base + 18874368);          // alias (after A0 dead)
  _Float16* WxT0 = (_Float16*)(base + 40108032);          // R1
  _Float16* hs0  = (_Float16*)(base + 40108032);          // alias (after WxT0 dead)
  _Float16* hs1  = (_Float16*)(base + 40108032);          // alias (after hs0 dead)
  _Float16* Zx   = (_Float16*)(base + 82575360);          // R2
  _Float16* WhT0 = (_Float16*)(base + 233570304);         // R3
  _Float16* WhT1 = (_Float16*)(base + 233570304);         // alias (after WhT0 dead)
  float*    biasn= (float*)   (base + 254859264);         // [4][4608]
  _Float16* Hb   = (_Float16*)(base + 254932992);         // [2 phase][2][64][1152]
  float*    Cb   = (float*)   (base + 255522816);         // [2][64][1152]

  int tot0 = NQ*2304 + 4620*KH;
  int tot1 = NQ*1152 + 4620*KH;

  // ---- packs (layer 0 only; layer 1 weights packed after L0 finishes) ----
  k_cast_f16<<<18874368/4/256, 256, 0, stream>>>(x, A0, 18874368/4);
  k_pack_w2<<<(tot0+255)/256,256,0,stream>>>(w_f0, WxT0,                   WhT0,           256, tot0);
  k_pack_w2<<<(tot0+255)/256,256,0,stream>>>(w_b0, WxT0 + (size_t)NQ*2304, WhT0 + 4620*KH, 256, tot0);
  k_pack_bias<<<(4*NQ+255)/256,256,0,stream>>>(b_f0,b_b0,b_f1,b_b1, biasn);

  // ---- layer 0 ----
  (void)hipMemsetAsync(Hb, 0, 589824, stream);
  (void)hipMemsetAsync(Cb, 0, 589824, stream);
  k_gemm<<<4608, 256, 0, stream>>>(A0, WxT0, Zx, biasn, 2304);
  for (int s=0; s<T_; ++s){
    _Float16* hin  = Hb + (size_t)(s&1)*(2*B_*KH);
    _Float16* hout = Hb + (size_t)((s&1)^1)*(2*B_*KH);
    k_step<<<256,256,0,stream>>>(WhT0, Zx, hin, hout, Cb, hs0, s);
  }

  // ---- layer 1 packs (WhT0/A0 now dead; R3 and R_A reused) ----
  k_pack_w2<<<(tot1+255)/256,256,0,stream>>>(w_f1, WxT1,                   WhT1,           128, tot1);
  k_pack_w2<<<(tot1+255)/256,256,0,stream>>>(w_b1, WxT1 + (size_t)NQ*1152, WhT1 + 4620*KH, 128, tot1);
  k_pack_A1<<<(NROWS*KH/8+255)/256,256,0,stream>>>(hs0, A1, NROWS*KH/8);

  // ---- layer 1 ----
  (void)hipMemsetAsync(Hb, 0, 589824, stream);
  (void)hipMemsetAsync(Cb, 0, 589824, stream);
  k_gemm<<<4608, 256, 0, stream>>>(A1, WxT1, Zx, biasn + 2*NQ, 1152);
  for (int s=0; s<T_; ++s){
    _Float16* hin  = Hb + (size_t)(s&1)*(2*B_*KH);
    _Float16* hout = Hb + (size_t)((s&1)^1)*(2*B_*KH);
    k_step<<<256,256,0,stream>>>(WhT1, Zx, hin, hout, Cb, hs1, s);
  }

  // ---- FC ----
  k_fc<<<NROWS, 64, 0, stream>>>(hs1, fc_w, fc_b, out);
}